// Round 1
// baseline (354.521 us; speedup 1.0000x reference)
//
#include <hip/hip_runtime.h>

// Problem constants
#define NB   32
#define LSEQ 512
#define DIN1 384
#define FOUT 256
#define TMEL 2048

// ---------------------------------------------------------------------------
// Weight transpose: Bt[k*256 + f] = w[f*(3D) + (k%D)*3 + k/D], k in [0, 3D)
// Maps conv weight [F, D, 3] -> GEMM B [K=3D, F] with k = kc*D + d ordering.
// ---------------------------------------------------------------------------
__global__ void transpose_w_kernel(const float* __restrict__ w,
                                   float* __restrict__ Bt, int D) {
    int e = blockIdx.x * 256 + threadIdx.x;   // over K*256
    int k = e >> 8, f = e & 255;
    int d = k % D, kc = k / D;
    Bt[e] = w[f * (3 * D) + d * 3 + kc];
}

// ---------------------------------------------------------------------------
// Fused conv1d(K=3,pad=1) + bias + LayerNorm + ReLU (+ optional lin_w dot)
// GEMM: out[m][f] = sum_k A[m][k] * Bt[k][f]
//   A[m][k] = in[n, l + k/DIN - 1, k%DIN]   (zero outside [0,512))
// BM=32, BN=256 (full F, so LN is in-block), BK=16, 256 threads, 4x8 acc.
// MODE 0: write h = relu(LN(conv)) to out [M,256]
// MODE 1: write dpo[m] = dot(relu(LN(conv)), lin_w) + lin_b to out [M]
// ---------------------------------------------------------------------------
template<int DIN, int MODE>
__global__ __launch_bounds__(256, 2) void conv_ln_kernel(
    const float* __restrict__ in,    // [N*512, DIN]
    const float* __restrict__ Bt,    // [3*DIN, 256]
    const float* __restrict__ cb,    // conv bias [256]
    const float* __restrict__ g,     // ln gamma [256]
    const float* __restrict__ bb,    // ln beta  [256]
    const float* __restrict__ lw,    // lin_w [256] (MODE 1)
    const float* __restrict__ lbp,   // lin_b scalar ptr (MODE 1)
    float* __restrict__ out)
{
    const int K = 3 * DIN;
    __shared__ float As[32][16];
    __shared__ float Bs[16][256];

    const int tid = threadIdx.x;
    const int m0  = blockIdx.x * 32;
    const int tr4 = (tid >> 5) * 4;       // 4 rows per thread
    const int tc4 = (tid & 31) * 4;       // cols tc4..tc4+3 and +128

    float acc[4][8];
    #pragma unroll
    for (int i = 0; i < 4; i++)
        #pragma unroll
        for (int j = 0; j < 8; j++) acc[i][j] = 0.f;

    // A-tile load mapping: 32x16 floats, float2 per thread
    const int ar  = tid >> 3;             // row 0..31
    const int akl = (tid & 7) * 2;        // k_local {0,2,..,14}
    const int am  = m0 + ar;
    const int an  = am >> 9;
    const int al  = am & 511;

    // B-tile load mapping: 16x256 floats, 4x float4 per thread
    const int brow = tid >> 4;            // 0..15
    const int bcol = (tid & 15) * 16;

    for (int k0 = 0; k0 < K; k0 += 16) {
        // ---- load tiles to registers ----
        int kg = k0 + akl;
        int lp = al + kg / DIN - 1;
        int d  = kg % DIN;
        float2 av = make_float2(0.f, 0.f);
        if (lp >= 0 && lp < 512)
            av = *(const float2*)&in[((an << 9) + lp) * DIN + d];

        float4 bv[4];
        const float* bsrc = &Bt[(k0 + brow) * 256 + bcol];
        #pragma unroll
        for (int q = 0; q < 4; q++) bv[q] = *(const float4*)&bsrc[q * 4];

        __syncthreads();
        *(float2*)&As[ar][akl] = av;
        #pragma unroll
        for (int q = 0; q < 4; q++) *(float4*)&Bs[brow][bcol + q * 4] = bv[q];
        __syncthreads();

        // ---- compute ----
        #pragma unroll
        for (int kk = 0; kk < 16; kk++) {
            float a[4];
            #pragma unroll
            for (int i = 0; i < 4; i++) a[i] = As[tr4 + i][kk];
            float4 b0 = *(const float4*)&Bs[kk][tc4];
            float4 b1 = *(const float4*)&Bs[kk][tc4 + 128];
            #pragma unroll
            for (int i = 0; i < 4; i++) {
                acc[i][0] = fmaf(a[i], b0.x, acc[i][0]);
                acc[i][1] = fmaf(a[i], b0.y, acc[i][1]);
                acc[i][2] = fmaf(a[i], b0.z, acc[i][2]);
                acc[i][3] = fmaf(a[i], b0.w, acc[i][3]);
                acc[i][4] = fmaf(a[i], b1.x, acc[i][4]);
                acc[i][5] = fmaf(a[i], b1.y, acc[i][5]);
                acc[i][6] = fmaf(a[i], b1.z, acc[i][6]);
                acc[i][7] = fmaf(a[i], b1.w, acc[i][7]);
            }
        }
    }

    // ---- epilogue: bias + LayerNorm + ReLU (+ linear dot) ----
    const int c0 = tc4, c1 = tc4 + 128;
    float cbv[8], gv[8], bbv[8], lwv[8];
    #pragma unroll
    for (int j = 0; j < 4; j++) {
        cbv[j] = cb[c0 + j];  cbv[4 + j] = cb[c1 + j];
        gv[j]  = g[c0 + j];   gv[4 + j]  = g[c1 + j];
        bbv[j] = bb[c0 + j];  bbv[4 + j] = bb[c1 + j];
    }
    if (MODE == 1) {
        #pragma unroll
        for (int j = 0; j < 4; j++) { lwv[j] = lw[c0 + j]; lwv[4 + j] = lw[c1 + j]; }
    }
    float linb = 0.f;
    if (MODE == 1) linb = lbp[0];

    #pragma unroll
    for (int i = 0; i < 4; i++) {
        float vals[8];
        float s = 0.f, sq = 0.f;
        #pragma unroll
        for (int j = 0; j < 8; j++) {
            float v = acc[i][j] + cbv[j];
            vals[j] = v; s += v; sq += v * v;
        }
        #pragma unroll
        for (int msk = 1; msk < 32; msk <<= 1) {
            s  += __shfl_xor(s, msk);
            sq += __shfl_xor(sq, msk);
        }
        float mean = s * (1.f / 256.f);
        float var  = sq * (1.f / 256.f) - mean * mean;
        float rs   = rsqrtf(var + 1e-5f);
        int m = m0 + tr4 + i;

        if (MODE == 0) {
            float ov[8];
            #pragma unroll
            for (int j = 0; j < 8; j++)
                ov[j] = fmaxf(0.f, (vals[j] - mean) * rs * gv[j] + bbv[j]);
            *(float4*)&out[m * 256 + c0] = make_float4(ov[0], ov[1], ov[2], ov[3]);
            *(float4*)&out[m * 256 + c1] = make_float4(ov[4], ov[5], ov[6], ov[7]);
        } else {
            float p = 0.f;
            #pragma unroll
            for (int j = 0; j < 8; j++)
                p += fmaxf(0.f, (vals[j] - mean) * rs * gv[j] + bbv[j]) * lwv[j];
            #pragma unroll
            for (int msk = 1; msk < 32; msk <<= 1) p += __shfl_xor(p, msk);
            if ((tid & 31) == 0) out[m] = p + linb;
        }
    }
}

// ---------------------------------------------------------------------------
// LR phase 1: per-batch cumsum (Hillis-Steele over 512) + searchsorted-right
// idxv[n*T + t] = (t < total) ? min(first j with c[j] > t, 511) : -1
// ---------------------------------------------------------------------------
__global__ void lr_idx_kernel(const int* __restrict__ target,
                              int* __restrict__ idxv) {
    __shared__ int c[512];
    const int n = blockIdx.x, tid = threadIdx.x;
    c[tid]       = target[n * 512 + tid];
    c[tid + 256] = target[n * 512 + 256 + tid];
    __syncthreads();
    for (int off = 1; off < 512; off <<= 1) {
        int v0 = (tid       >= off) ? c[tid       - off] : 0;
        int v1 = (tid + 256 >= off) ? c[tid + 256 - off] : 0;
        __syncthreads();
        c[tid]       += v0;
        c[tid + 256] += v1;
        __syncthreads();
    }
    const int total = c[511];
    for (int t = tid; t < TMEL; t += 256) {
        int lo = 0, hi = 512;
        while (lo < hi) {
            int mid = (lo + hi) >> 1;
            if (c[mid] <= t) lo = mid + 1; else hi = mid;
        }
        idxv[n * TMEL + t] = (t < total) ? min(lo, 511) : -1;
    }
}

// ---------------------------------------------------------------------------
// LR phase 2: gather rows of x -> out [N, T, 384], float4 per thread
// ---------------------------------------------------------------------------
__global__ void lr_gather_kernel(const float* __restrict__ x,
                                 const int* __restrict__ idxv,
                                 float* __restrict__ out) {
    int gid = blockIdx.x * 256 + threadIdx.x;   // over N*T*384/4 = 6291456
    int f4  = gid % 96;
    int row = gid / 96;                          // n*2048 + t
    int n   = row >> 11;
    int ie  = idxv[row];
    float4 v = make_float4(0.f, 0.f, 0.f, 0.f);
    if (ie >= 0)
        v = *(const float4*)&x[(((n << 9) + ie) * 384) + f4 * 4];
    *(float4*)&out[(size_t)row * 384 + f4 * 4] = v;
}

// ---------------------------------------------------------------------------
extern "C" void kernel_launch(void* const* d_in, const int* in_sizes, int n_in,
                              void* d_out, int out_size, void* d_ws, size_t ws_size,
                              hipStream_t stream) {
    const float* x   = (const float*)d_in[0];
    const float* w1  = (const float*)d_in[1];
    const float* b1  = (const float*)d_in[2];
    const float* g1  = (const float*)d_in[3];
    const float* bb1 = (const float*)d_in[4];
    const float* w2  = (const float*)d_in[5];
    const float* b2  = (const float*)d_in[6];
    const float* g2  = (const float*)d_in[7];
    const float* bb2 = (const float*)d_in[8];
    const float* lw  = (const float*)d_in[9];
    const float* lb  = (const float*)d_in[10];
    const int* target = (const int*)d_in[11];
    // d_in[12] = mel_max_length (2048, static shape)

    float* ws  = (float*)d_ws;
    float* Bt1 = ws;                      // 1152*256 = 294912
    float* Bt2 = ws + 294912;             // 768*256  = 196608
    float* h1  = ws + 491520;             // 16384*256 = 4194304
    int*  idxv = (int*)(ws + 4685824);    // 65536 ints

    float* out0 = (float*)d_out;          // [32, 2048, 384]
    float* dpo  = out0 + 32 * 2048 * 384; // [32, 512]

    transpose_w_kernel<<<1152, 256, 0, stream>>>(w1, Bt1, 384);
    transpose_w_kernel<<<768,  256, 0, stream>>>(w2, Bt2, 256);

    conv_ln_kernel<384, 0><<<512, 256, 0, stream>>>(x,  Bt1, b1, g1, bb1,
                                                    nullptr, nullptr, h1);
    conv_ln_kernel<256, 1><<<512, 256, 0, stream>>>(h1, Bt2, b2, g2, bb2,
                                                    lw, lb, dpo);

    lr_idx_kernel<<<NB, 256, 0, stream>>>(target, idxv);
    lr_gather_kernel<<<24576, 256, 0, stream>>>(x, idxv, out0);
}

// Round 2
// 95.873 us; speedup vs baseline: 3.6978x; 3.6978x over previous
//
#include <hip/hip_runtime.h>
#include <hip/hip_bf16.h>

#define NB   32
#define TMEL 2048

typedef unsigned short u16;
typedef short s8v __attribute__((ext_vector_type(8)));
typedef float f4v __attribute__((ext_vector_type(4)));
typedef u16 u16x8 __attribute__((ext_vector_type(8)));

static __device__ __forceinline__ u16 f2bf(float v) {
    __hip_bfloat16 h = __float2bfloat16(v);
    return *(u16*)&h;
}

// ---------------------------------------------------------------------------
// x (f32) -> bf16, 8 elems/thread
// ---------------------------------------------------------------------------
__global__ void cvt_x_kernel(const float* __restrict__ in, u16* __restrict__ out) {
    int i = blockIdx.x * 256 + threadIdx.x;       // over n/8
    const float4* p = (const float4*)(in + (size_t)i * 8);
    float4 v0 = p[0], v1 = p[1];
    float vv[8] = {v0.x, v0.y, v0.z, v0.w, v1.x, v1.y, v1.z, v1.w};
    u16x8 r;
    #pragma unroll
    for (int j = 0; j < 8; j++) r[j] = f2bf(vv[j]);
    *(u16x8*)(out + (size_t)i * 8) = r;
}

// ---------------------------------------------------------------------------
// Wt[f][kc*DIN + d] = bf16(w[f][d][kc]);  w is [256][DIN][3]
// ---------------------------------------------------------------------------
__global__ void prep_w_kernel(const float* __restrict__ w, u16* __restrict__ Wt,
                              int DIN) {
    int e = blockIdx.x * 256 + threadIdx.x;       // over 256*K
    int K = 3 * DIN;
    int f = e / K;
    int rem = e - f * K;
    int kc = rem / DIN;
    int d = rem - kc * DIN;
    Wt[e] = f2bf(w[f * K + d * 3 + kc]);
}

// ---------------------------------------------------------------------------
// Fused conv1d(K=3,pad=1) as MFMA GEMM + bias + LayerNorm + ReLU (+ lin dot)
// out[m][f] = sum_k A[m][k] * B[k][f],  A[m][k] = Ain[n, l+kc-1, d] (0 padded)
// k = kc*DIN + d.  Tile 64(M) x 256(F) x BK=64.  512 thr = 8 waves (2x4).
// Wave (wr,wc): rows 32*wr..+31, cols 64*wc..+63 -> 2x4 frags of 16x16x32.
// LDS: As[64 rows][128B], Bs[256 rows][128B], both slot^=(row&7) swizzled;
// staged via global_load_lds(16B) with pre-swizzled per-lane source.
// MODE 0: write bf16 h to out [M][256].  MODE 1: dpo[m] = dot(h, lin_w)+lin_b.
// ---------------------------------------------------------------------------
template<int DIN, int MODE>
__global__ __launch_bounds__(512, 2) void conv_mfma_kernel(
    const u16* __restrict__ Ain,   // [N*512][DIN] bf16
    const u16* __restrict__ Wt,    // [256][3*DIN] bf16
    const float* __restrict__ cb,
    const float* __restrict__ g,
    const float* __restrict__ bb,
    const float* __restrict__ lw,
    const float* __restrict__ lbp,
    const u16* __restrict__ zbuf,  // >=16B zeros
    void* __restrict__ outp)
{
    const int K = 3 * DIN;
    __shared__ __align__(128) char AsB[64 * 128];    // 8 KB
    __shared__ __align__(128) char BsB[256 * 128];   // 32 KB
    __shared__ float redS[64 * 4];
    __shared__ float redQ[64 * 4];
    __shared__ float redP[64 * 4];

    const int tid  = threadIdx.x;
    const int lane = tid & 63, w = tid >> 6;
    const int lr = lane & 15, q4 = lane >> 4;
    const int wr = w >> 2, wc = w & 3;
    const int m0 = blockIdx.x * 64;
    const int n  = m0 >> 9, l0 = m0 & 511;

    f4v acc[2][4];
    #pragma unroll
    for (int mi = 0; mi < 2; mi++)
        #pragma unroll
        for (int ni = 0; ni < 4; ni++) acc[mi][ni] = {0.f, 0.f, 0.f, 0.f};

    // A staging map: dest byte = tid*16; row = tid>>3; slot = tid&7 (swizzled src)
    const int a_r    = tid >> 3;
    const int a_slot = (tid & 7) ^ (a_r & 7);
    // B staging map: round q: dest byte = q*8192 + tid*16; row = q*64 + (tid>>3)
    const int b_r0   = tid >> 3;
    const int b_slot = (tid & 7) ^ (b_r0 & 7);   // (q*64)&7 == 0 -> same all rounds

    // fragment read offsets (swizzled)
    const int aoff0 = (32 * wr + lr) * 128;
    const int aoff1 = (32 * wr + 16 + lr) * 128;
    int boff[4];
    #pragma unroll
    for (int ni = 0; ni < 4; ni++) boff[ni] = (64 * wc + 16 * ni + lr) * 128;
    const int slot0 = ((q4)     ^ (lr & 7)) << 4;
    const int slot1 = ((q4 | 4) ^ (lr & 7)) << 4;

    for (int s = 0; s < K / 64; ++s) {
        const int k0 = s * 64;
        const int kc = k0 / DIN;
        const int d0 = k0 - kc * DIN;

        const int lp = l0 + a_r + kc - 1;
        const u16* asrc = (lp >= 0 && lp < 512)
            ? (Ain + ((size_t)((n << 9) + lp)) * DIN + d0 + a_slot * 8)
            : zbuf;
        const u16* bsrc = Wt + (size_t)b_r0 * K + k0 + b_slot * 8;

        __syncthreads();   // previous tile's readers done
        __builtin_amdgcn_global_load_lds(
            (const __attribute__((address_space(1))) void*)asrc,
            (__attribute__((address_space(3))) void*)(AsB + w * 1024), 16, 0, 0);
        #pragma unroll
        for (int q = 0; q < 4; q++) {
            __builtin_amdgcn_global_load_lds(
                (const __attribute__((address_space(1))) void*)(bsrc + (size_t)q * 64 * K),
                (__attribute__((address_space(3))) void*)(BsB + q * 8192 + w * 1024),
                16, 0, 0);
        }
        __syncthreads();   // compiler drains vmcnt(0) before barrier

        #pragma unroll
        for (int kk = 0; kk < 2; kk++) {
            const int sl = kk ? slot1 : slot0;
            s8v a0 = *(const s8v*)(AsB + aoff0 + sl);
            s8v a1 = *(const s8v*)(AsB + aoff1 + sl);
            s8v b0 = *(const s8v*)(BsB + boff[0] + sl);
            s8v b1 = *(const s8v*)(BsB + boff[1] + sl);
            s8v b2 = *(const s8v*)(BsB + boff[2] + sl);
            s8v b3 = *(const s8v*)(BsB + boff[3] + sl);
            acc[0][0] = __builtin_amdgcn_mfma_f32_16x16x32_bf16(a0, b0, acc[0][0], 0, 0, 0);
            acc[0][1] = __builtin_amdgcn_mfma_f32_16x16x32_bf16(a0, b1, acc[0][1], 0, 0, 0);
            acc[0][2] = __builtin_amdgcn_mfma_f32_16x16x32_bf16(a0, b2, acc[0][2], 0, 0, 0);
            acc[0][3] = __builtin_amdgcn_mfma_f32_16x16x32_bf16(a0, b3, acc[0][3], 0, 0, 0);
            acc[1][0] = __builtin_amdgcn_mfma_f32_16x16x32_bf16(a1, b0, acc[1][0], 0, 0, 0);
            acc[1][1] = __builtin_amdgcn_mfma_f32_16x16x32_bf16(a1, b1, acc[1][1], 0, 0, 0);
            acc[1][2] = __builtin_amdgcn_mfma_f32_16x16x32_bf16(a1, b2, acc[1][2], 0, 0, 0);
            acc[1][3] = __builtin_amdgcn_mfma_f32_16x16x32_bf16(a1, b3, acc[1][3], 0, 0, 0);
        }
    }

    // ---- epilogue: bias + LN + ReLU (+ dot) ----
    // acc[mi][ni][reg] = C[m0 + 32wr + 16mi + 4*q4 + reg][64wc + 16ni + lr]
    float cbv[4], gv[4], bbv[4], lwv[4];
    int col[4];
    #pragma unroll
    for (int ni = 0; ni < 4; ni++) {
        col[ni] = 64 * wc + 16 * ni + lr;
        cbv[ni] = cb[col[ni]]; gv[ni] = g[col[ni]]; bbv[ni] = bb[col[ni]];
        if (MODE == 1) lwv[ni] = lw[col[ni]];
    }

    float sv[2][4], sq[2][4];
    #pragma unroll
    for (int mi = 0; mi < 2; mi++)
        #pragma unroll
        for (int reg = 0; reg < 4; reg++) {
            float s = 0.f, q = 0.f;
            #pragma unroll
            for (int ni = 0; ni < 4; ni++) {
                float v = acc[mi][ni][reg] + cbv[ni];
                s += v; q += v * v;
            }
            #pragma unroll
            for (int msk = 1; msk < 16; msk <<= 1) {
                s += __shfl_xor(s, msk);
                q += __shfl_xor(q, msk);
            }
            sv[mi][reg] = s; sq[mi][reg] = q;
        }
    if (lr == 0) {
        #pragma unroll
        for (int mi = 0; mi < 2; mi++)
            #pragma unroll
            for (int reg = 0; reg < 4; reg++) {
                int rl = 32 * wr + 16 * mi + 4 * q4 + reg;
                redS[rl * 4 + wc] = sv[mi][reg];
                redQ[rl * 4 + wc] = sq[mi][reg];
            }
    }
    __syncthreads();

    float mean_[2][4], rs_[2][4];
    #pragma unroll
    for (int mi = 0; mi < 2; mi++)
        #pragma unroll
        for (int reg = 0; reg < 4; reg++) {
            int rl = 32 * wr + 16 * mi + 4 * q4 + reg;
            float4 ps = *(float4*)&redS[rl * 4];
            float4 pq = *(float4*)&redQ[rl * 4];
            float mean = (ps.x + ps.y + ps.z + ps.w) * (1.f / 256.f);
            float var  = (pq.x + pq.y + pq.z + pq.w) * (1.f / 256.f) - mean * mean;
            mean_[mi][reg] = mean;
            rs_[mi][reg]   = rsqrtf(var + 1e-5f);
        }

    if (MODE == 0) {
        u16* hout = (u16*)outp;
        #pragma unroll
        for (int mi = 0; mi < 2; mi++)
            #pragma unroll
            for (int reg = 0; reg < 4; reg++) {
                int rl = 32 * wr + 16 * mi + 4 * q4 + reg;
                #pragma unroll
                for (int ni = 0; ni < 4; ni++) {
                    float v = acc[mi][ni][reg] + cbv[ni];
                    float o = fmaxf(0.f, (v - mean_[mi][reg]) * rs_[mi][reg] * gv[ni] + bbv[ni]);
                    hout[(size_t)(m0 + rl) * 256 + col[ni]] = f2bf(o);
                }
            }
    } else {
        float pp[2][4];
        #pragma unroll
        for (int mi = 0; mi < 2; mi++)
            #pragma unroll
            for (int reg = 0; reg < 4; reg++) {
                float p = 0.f;
                #pragma unroll
                for (int ni = 0; ni < 4; ni++) {
                    float v = acc[mi][ni][reg] + cbv[ni];
                    float o = fmaxf(0.f, (v - mean_[mi][reg]) * rs_[mi][reg] * gv[ni] + bbv[ni]);
                    p += o * lwv[ni];
                }
                #pragma unroll
                for (int msk = 1; msk < 16; msk <<= 1) p += __shfl_xor(p, msk);
                pp[mi][reg] = p;
            }
        if (lr == 0) {
            #pragma unroll
            for (int mi = 0; mi < 2; mi++)
                #pragma unroll
                for (int reg = 0; reg < 4; reg++) {
                    int rl = 32 * wr + 16 * mi + 4 * q4 + reg;
                    redP[rl * 4 + wc] = pp[mi][reg];
                }
        }
        __syncthreads();
        if (tid < 64) {
            float* dpo = (float*)outp;
            float4 p4 = *(float4*)&redP[tid * 4];
            dpo[m0 + tid] = p4.x + p4.y + p4.z + p4.w + lbp[0];
        }
    }
}

// ---------------------------------------------------------------------------
// LR phase 1: per-batch cumsum + searchsorted-right
// ---------------------------------------------------------------------------
__global__ void lr_idx_kernel(const int* __restrict__ target,
                              int* __restrict__ idxv) {
    __shared__ int c[512];
    const int n = blockIdx.x, tid = threadIdx.x;
    c[tid]       = target[n * 512 + tid];
    c[tid + 256] = target[n * 512 + 256 + tid];
    __syncthreads();
    for (int off = 1; off < 512; off <<= 1) {
        int v0 = (tid       >= off) ? c[tid       - off] : 0;
        int v1 = (tid + 256 >= off) ? c[tid + 256 - off] : 0;
        __syncthreads();
        c[tid]       += v0;
        c[tid + 256] += v1;
        __syncthreads();
    }
    const int total = c[511];
    for (int t = tid; t < TMEL; t += 256) {
        int lo = 0, hi = 512;
        while (lo < hi) {
            int mid = (lo + hi) >> 1;
            if (c[mid] <= t) lo = mid + 1; else hi = mid;
        }
        idxv[n * TMEL + t] = (t < total) ? min(lo, 511) : -1;
    }
}

// ---------------------------------------------------------------------------
// LR phase 2: gather rows of x -> out [N, T, 384]
// ---------------------------------------------------------------------------
__global__ void lr_gather_kernel(const float* __restrict__ x,
                                 const int* __restrict__ idxv,
                                 float* __restrict__ out) {
    int gid = blockIdx.x * 256 + threadIdx.x;   // over N*T*96
    int f4  = gid % 96;
    int row = gid / 96;
    int n   = row >> 11;
    int ie  = idxv[row];
    float4 v = make_float4(0.f, 0.f, 0.f, 0.f);
    if (ie >= 0)
        v = *(const float4*)&x[(((size_t)(n << 9) + ie) * 384) + f4 * 4];
    *(float4*)&out[(size_t)row * 384 + f4 * 4] = v;
}

// ---------------------------------------------------------------------------
extern "C" void kernel_launch(void* const* d_in, const int* in_sizes, int n_in,
                              void* d_out, int out_size, void* d_ws, size_t ws_size,
                              hipStream_t stream) {
    const float* x   = (const float*)d_in[0];
    const float* w1  = (const float*)d_in[1];
    const float* b1  = (const float*)d_in[2];
    const float* g1  = (const float*)d_in[3];
    const float* bb1 = (const float*)d_in[4];
    const float* w2  = (const float*)d_in[5];
    const float* b2  = (const float*)d_in[6];
    const float* g2  = (const float*)d_in[7];
    const float* bb2 = (const float*)d_in[8];
    const float* lw  = (const float*)d_in[9];
    const float* lb  = (const float*)d_in[10];
    const int* target = (const int*)d_in[11];

    // ws layout (bytes): zbuf 128 | Wt1 589824 | Wt2 393216 | xb 12582912 | idxv 262144
    char* wsb  = (char*)d_ws;
    u16*  zbuf = (u16*)wsb;
    u16*  Wt1  = (u16*)(wsb + 128);
    u16*  Wt2  = (u16*)(wsb + 128 + 589824);
    u16*  xb   = (u16*)(wsb + 128 + 589824 + 393216);
    int*  idxv = (int*)(wsb + 128 + 589824 + 393216 + 12582912);

    float* out0 = (float*)d_out;                  // [32, 2048, 384]
    float* dpo  = out0 + (size_t)32 * 2048 * 384; // [32, 512]
    // h1 scratch lives in the d_out region (gather fully overwrites it later)
    u16* h1 = (u16*)d_out;                        // 16384*256 bf16 = 8 MB

    hipMemsetAsync(zbuf, 0, 128, stream);
    cvt_x_kernel<<<3072, 256, 0, stream>>>(x, xb);          // 6291456/8/256
    prep_w_kernel<<<1152, 256, 0, stream>>>(w1, Wt1, 384);  // 256*1152/256
    prep_w_kernel<<<768,  256, 0, stream>>>(w2, Wt2, 256);

    conv_mfma_kernel<384, 0><<<256, 512, 0, stream>>>(
        xb, Wt1, b1, g1, bb1, nullptr, nullptr, zbuf, (void*)h1);
    conv_mfma_kernel<256, 1><<<256, 512, 0, stream>>>(
        h1, Wt2, b2, g2, bb2, lw, lb, zbuf, (void*)dpo);

    lr_idx_kernel<<<NB, 256, 0, stream>>>(target, idxv);
    lr_gather_kernel<<<24576, 256, 0, stream>>>(x, idxv, out0);
}

// Round 4
// 86.410 us; speedup vs baseline: 4.1028x; 1.1095x over previous
//
#include <hip/hip_runtime.h>
#include <hip/hip_bf16.h>

#define NB   32
#define TMEL 2048

typedef unsigned short u16;
typedef short s8v __attribute__((ext_vector_type(8)));
typedef float f4v __attribute__((ext_vector_type(4)));
typedef u16 u16x8 __attribute__((ext_vector_type(8)));

static __device__ __forceinline__ u16 f2bf(float v) {
    __hip_bfloat16 h = __float2bfloat16(v);
    return *(u16*)&h;
}

// ---------------------------------------------------------------------------
// Fused prep: x->bf16 (blocks [0,3072)), w1 transpose (blocks [3072,4224)),
// w2 transpose (blocks [4224,4992)), zbuf zeroing (block 0, tid<8).
// Wt[f][kc*DIN + d] = bf16(w[f][d][kc]);  w is [256][DIN][3]
// ---------------------------------------------------------------------------
__global__ __launch_bounds__(256) void prep_kernel(
    const float* __restrict__ x,
    const float* __restrict__ w1,
    const float* __restrict__ w2,
    u16* __restrict__ xb,
    u16* __restrict__ Wt1,
    u16* __restrict__ Wt2,
    u16* __restrict__ zbuf)
{
    const int b = blockIdx.x, tid = threadIdx.x;
    if (b == 0 && tid < 8) {
        u16x8 z = {0, 0, 0, 0, 0, 0, 0, 0};
        *(u16x8*)(zbuf + tid * 8) = z;
    }
    if (b < 3072) {
        int i = b * 256 + tid;                    // over 6291456/8
        const f4v* p = (const f4v*)(x + (size_t)i * 8);
        f4v v0 = p[0], v1 = p[1];
        float vv[8] = {v0[0], v0[1], v0[2], v0[3], v1[0], v1[1], v1[2], v1[3]};
        u16x8 r;
        #pragma unroll
        for (int j = 0; j < 8; j++) r[j] = f2bf(vv[j]);
        *(u16x8*)(xb + (size_t)i * 8) = r;
    } else if (b < 3072 + 1152) {
        const int K = 1152, DIN = 384;
        int e = (b - 3072) * 256 + tid;           // over 256*1152
        int f = e / K;
        int rem = e - f * K;
        int kc = rem / DIN;
        int d = rem - kc * DIN;
        Wt1[e] = f2bf(w1[f * K + d * 3 + kc]);
    } else {
        const int K = 768, DIN = 256;
        int e = (b - 4224) * 256 + tid;           // over 256*768
        int f = e / K;
        int rem = e - f * K;
        int kc = rem / DIN;
        int d = rem - kc * DIN;
        Wt2[e] = f2bf(w2[f * K + d * 3 + kc]);
    }
}

// ---------------------------------------------------------------------------
// Fused conv1d(K=3,pad=1) as MFMA GEMM + bias + LayerNorm + ReLU (+ lin dot)
// out[m][f] = sum_k A[m][k] * B[k][f],  A[m][k] = Ain[n, l+kc-1, d] (0 padded)
// k = kc*DIN + d.  Tile 64(M) x 256(F) x BK=64.  512 thr = 8 waves (2x4).
// Wave (wr,wc): rows 32*wr..+31, cols 64*wc..+63 -> 2x4 frags of 16x16x32.
// LDS: As[64 rows][128B], Bs[256 rows][128B], both slot^=(row&7) swizzled;
// staged via global_load_lds(16B) with pre-swizzled per-lane source.
// MODE 0: write bf16 h to out [M][256].  MODE 1: dpo[m] = dot(h, lin_w)+lin_b.
// ---------------------------------------------------------------------------
template<int DIN, int MODE>
__global__ __launch_bounds__(512, 2) void conv_mfma_kernel(
    const u16* __restrict__ Ain,   // [N*512][DIN] bf16
    const u16* __restrict__ Wt,    // [256][3*DIN] bf16
    const float* __restrict__ cb,
    const float* __restrict__ g,
    const float* __restrict__ bb,
    const float* __restrict__ lw,
    const float* __restrict__ lbp,
    const u16* __restrict__ zbuf,  // >=16B zeros
    void* __restrict__ outp)
{
    const int K = 3 * DIN;
    __shared__ __align__(128) char AsB[64 * 128];    // 8 KB
    __shared__ __align__(128) char BsB[256 * 128];   // 32 KB
    __shared__ float redS[64 * 4];
    __shared__ float redQ[64 * 4];
    __shared__ float redP[64 * 4];

    const int tid  = threadIdx.x;
    const int lane = tid & 63, w = tid >> 6;
    const int lr = lane & 15, q4 = lane >> 4;
    const int wr = w >> 2, wc = w & 3;
    const int m0 = blockIdx.x * 64;
    const int n  = m0 >> 9, l0 = m0 & 511;

    f4v acc[2][4];
    #pragma unroll
    for (int mi = 0; mi < 2; mi++)
        #pragma unroll
        for (int ni = 0; ni < 4; ni++) acc[mi][ni] = {0.f, 0.f, 0.f, 0.f};

    // A staging map: dest byte = tid*16; row = tid>>3; slot = tid&7 (swizzled src)
    const int a_r    = tid >> 3;
    const int a_slot = (tid & 7) ^ (a_r & 7);
    // B staging map: round q: dest byte = q*8192 + tid*16; row = q*64 + (tid>>3)
    const int b_r0   = tid >> 3;
    const int b_slot = (tid & 7) ^ (b_r0 & 7);   // (q*64)&7 == 0 -> same all rounds

    // fragment read offsets (swizzled)
    const int aoff0 = (32 * wr + lr) * 128;
    const int aoff1 = (32 * wr + 16 + lr) * 128;
    int boff[4];
    #pragma unroll
    for (int ni = 0; ni < 4; ni++) boff[ni] = (64 * wc + 16 * ni + lr) * 128;
    const int slot0 = ((q4)     ^ (lr & 7)) << 4;
    const int slot1 = ((q4 | 4) ^ (lr & 7)) << 4;

    for (int s = 0; s < K / 64; ++s) {
        const int k0 = s * 64;
        const int kc = k0 / DIN;
        const int d0 = k0 - kc * DIN;

        const int lp = l0 + a_r + kc - 1;
        const u16* asrc = (lp >= 0 && lp < 512)
            ? (Ain + ((size_t)((n << 9) + lp)) * DIN + d0 + a_slot * 8)
            : zbuf;
        const u16* bsrc = Wt + (size_t)b_r0 * K + k0 + b_slot * 8;

        __syncthreads();   // previous tile's readers done
        __builtin_amdgcn_global_load_lds(
            (const __attribute__((address_space(1))) void*)asrc,
            (__attribute__((address_space(3))) void*)(AsB + w * 1024), 16, 0, 0);
        #pragma unroll
        for (int q = 0; q < 4; q++) {
            __builtin_amdgcn_global_load_lds(
                (const __attribute__((address_space(1))) void*)(bsrc + (size_t)q * 64 * K),
                (__attribute__((address_space(3))) void*)(BsB + q * 8192 + w * 1024),
                16, 0, 0);
        }
        __syncthreads();   // compiler drains vmcnt(0) before barrier

        #pragma unroll
        for (int kk = 0; kk < 2; kk++) {
            const int sl = kk ? slot1 : slot0;
            s8v a0 = *(const s8v*)(AsB + aoff0 + sl);
            s8v a1 = *(const s8v*)(AsB + aoff1 + sl);
            s8v b0 = *(const s8v*)(BsB + boff[0] + sl);
            s8v b1 = *(const s8v*)(BsB + boff[1] + sl);
            s8v b2 = *(const s8v*)(BsB + boff[2] + sl);
            s8v b3 = *(const s8v*)(BsB + boff[3] + sl);
            acc[0][0] = __builtin_amdgcn_mfma_f32_16x16x32_bf16(a0, b0, acc[0][0], 0, 0, 0);
            acc[0][1] = __builtin_amdgcn_mfma_f32_16x16x32_bf16(a0, b1, acc[0][1], 0, 0, 0);
            acc[0][2] = __builtin_amdgcn_mfma_f32_16x16x32_bf16(a0, b2, acc[0][2], 0, 0, 0);
            acc[0][3] = __builtin_amdgcn_mfma_f32_16x16x32_bf16(a0, b3, acc[0][3], 0, 0, 0);
            acc[1][0] = __builtin_amdgcn_mfma_f32_16x16x32_bf16(a1, b0, acc[1][0], 0, 0, 0);
            acc[1][1] = __builtin_amdgcn_mfma_f32_16x16x32_bf16(a1, b1, acc[1][1], 0, 0, 0);
            acc[1][2] = __builtin_amdgcn_mfma_f32_16x16x32_bf16(a1, b2, acc[1][2], 0, 0, 0);
            acc[1][3] = __builtin_amdgcn_mfma_f32_16x16x32_bf16(a1, b3, acc[1][3], 0, 0, 0);
        }
    }

    // ---- epilogue: bias + LN + ReLU (+ dot) ----
    // acc[mi][ni][reg] = C[m0 + 32wr + 16mi + 4*q4 + reg][64wc + 16ni + lr]
    float cbv[4], gv[4], bbv[4], lwv[4];
    int col[4];
    #pragma unroll
    for (int ni = 0; ni < 4; ni++) {
        col[ni] = 64 * wc + 16 * ni + lr;
        cbv[ni] = cb[col[ni]]; gv[ni] = g[col[ni]]; bbv[ni] = bb[col[ni]];
        if (MODE == 1) lwv[ni] = lw[col[ni]];
    }

    float sv[2][4], sq[2][4];
    #pragma unroll
    for (int mi = 0; mi < 2; mi++)
        #pragma unroll
        for (int reg = 0; reg < 4; reg++) {
            float s = 0.f, q = 0.f;
            #pragma unroll
            for (int ni = 0; ni < 4; ni++) {
                float v = acc[mi][ni][reg] + cbv[ni];
                s += v; q += v * v;
            }
            #pragma unroll
            for (int msk = 1; msk < 16; msk <<= 1) {
                s += __shfl_xor(s, msk);
                q += __shfl_xor(q, msk);
            }
            sv[mi][reg] = s; sq[mi][reg] = q;
        }
    if (lr == 0) {
        #pragma unroll
        for (int mi = 0; mi < 2; mi++)
            #pragma unroll
            for (int reg = 0; reg < 4; reg++) {
                int rl = 32 * wr + 16 * mi + 4 * q4 + reg;
                redS[rl * 4 + wc] = sv[mi][reg];
                redQ[rl * 4 + wc] = sq[mi][reg];
            }
    }
    __syncthreads();

    float mean_[2][4], rs_[2][4];
    #pragma unroll
    for (int mi = 0; mi < 2; mi++)
        #pragma unroll
        for (int reg = 0; reg < 4; reg++) {
            int rl = 32 * wr + 16 * mi + 4 * q4 + reg;
            float4 ps = *(float4*)&redS[rl * 4];
            float4 pq = *(float4*)&redQ[rl * 4];
            float mean = (ps.x + ps.y + ps.z + ps.w) * (1.f / 256.f);
            float var  = (pq.x + pq.y + pq.z + pq.w) * (1.f / 256.f) - mean * mean;
            mean_[mi][reg] = mean;
            rs_[mi][reg]   = rsqrtf(var + 1e-5f);
        }

    if (MODE == 0) {
        u16* hout = (u16*)outp;
        #pragma unroll
        for (int mi = 0; mi < 2; mi++)
            #pragma unroll
            for (int reg = 0; reg < 4; reg++) {
                int rl = 32 * wr + 16 * mi + 4 * q4 + reg;
                #pragma unroll
                for (int ni = 0; ni < 4; ni++) {
                    float v = acc[mi][ni][reg] + cbv[ni];
                    float o = fmaxf(0.f, (v - mean_[mi][reg]) * rs_[mi][reg] * gv[ni] + bbv[ni]);
                    hout[(size_t)(m0 + rl) * 256 + col[ni]] = f2bf(o);
                }
            }
    } else {
        float pp[2][4];
        #pragma unroll
        for (int mi = 0; mi < 2; mi++)
            #pragma unroll
            for (int reg = 0; reg < 4; reg++) {
                float p = 0.f;
                #pragma unroll
                for (int ni = 0; ni < 4; ni++) {
                    float v = acc[mi][ni][reg] + cbv[ni];
                    float o = fmaxf(0.f, (v - mean_[mi][reg]) * rs_[mi][reg] * gv[ni] + bbv[ni]);
                    p += o * lwv[ni];
                }
                #pragma unroll
                for (int msk = 1; msk < 16; msk <<= 1) p += __shfl_xor(p, msk);
                pp[mi][reg] = p;
            }
        if (lr == 0) {
            #pragma unroll
            for (int mi = 0; mi < 2; mi++)
                #pragma unroll
                for (int reg = 0; reg < 4; reg++) {
                    int rl = 32 * wr + 16 * mi + 4 * q4 + reg;
                    redP[rl * 4 + wc] = pp[mi][reg];
                }
        }
        __syncthreads();
        if (tid < 64) {
            float* dpo = (float*)outp;
            float4 p4 = *(float4*)&redP[tid * 4];
            dpo[m0 + tid] = p4.x + p4.y + p4.z + p4.w + lbp[0];
        }
    }
}

// ---------------------------------------------------------------------------
// LR phase 1: per-batch cumsum + searchsorted-right
// ---------------------------------------------------------------------------
__global__ void lr_idx_kernel(const int* __restrict__ target,
                              int* __restrict__ idxv) {
    __shared__ int c[512];
    const int n = blockIdx.x, tid = threadIdx.x;
    c[tid]       = target[n * 512 + tid];
    c[tid + 256] = target[n * 512 + 256 + tid];
    __syncthreads();
    for (int off = 1; off < 512; off <<= 1) {
        int v0 = (tid       >= off) ? c[tid       - off] : 0;
        int v1 = (tid + 256 >= off) ? c[tid + 256 - off] : 0;
        __syncthreads();
        c[tid]       += v0;
        c[tid + 256] += v1;
        __syncthreads();
    }
    const int total = c[511];
    for (int t = tid; t < TMEL; t += 256) {
        int lo = 0, hi = 512;
        while (lo < hi) {
            int mid = (lo + hi) >> 1;
            if (c[mid] <= t) lo = mid + 1; else hi = mid;
        }
        idxv[n * TMEL + t] = (t < total) ? min(lo, 511) : -1;
    }
}

// ---------------------------------------------------------------------------
// LR phase 2: gather rows of x -> out [N, T, 384]; nontemporal stores via
// ext_vector f4v (HIP float4 is a class type the builtin rejects)
// ---------------------------------------------------------------------------
__global__ void lr_gather_kernel(const float* __restrict__ x,
                                 const int* __restrict__ idxv,
                                 float* __restrict__ out) {
    int gid = blockIdx.x * 256 + threadIdx.x;   // over N*T*96
    int f4  = gid % 96;
    int row = gid / 96;
    int n   = row >> 11;
    int ie  = idxv[row];
    f4v v = {0.f, 0.f, 0.f, 0.f};
    if (ie >= 0)
        v = *(const f4v*)&x[(((size_t)(n << 9) + ie) * 384) + f4 * 4];
    __builtin_nontemporal_store(v, (f4v*)&out[(size_t)row * 384 + f4 * 4]);
}

// ---------------------------------------------------------------------------
extern "C" void kernel_launch(void* const* d_in, const int* in_sizes, int n_in,
                              void* d_out, int out_size, void* d_ws, size_t ws_size,
                              hipStream_t stream) {
    const float* x   = (const float*)d_in[0];
    const float* w1  = (const float*)d_in[1];
    const float* b1  = (const float*)d_in[2];
    const float* g1  = (const float*)d_in[3];
    const float* bb1 = (const float*)d_in[4];
    const float* w2  = (const float*)d_in[5];
    const float* b2  = (const float*)d_in[6];
    const float* g2  = (const float*)d_in[7];
    const float* bb2 = (const float*)d_in[8];
    const float* lw  = (const float*)d_in[9];
    const float* lb  = (const float*)d_in[10];
    const int* target = (const int*)d_in[11];

    // ws layout (bytes): zbuf 128 | Wt1 589824 | Wt2 393216 | xb 12582912 | idxv 262144
    char* wsb  = (char*)d_ws;
    u16*  zbuf = (u16*)wsb;
    u16*  Wt1  = (u16*)(wsb + 128);
    u16*  Wt2  = (u16*)(wsb + 128 + 589824);
    u16*  xb   = (u16*)(wsb + 128 + 589824 + 393216);
    int*  idxv = (int*)(wsb + 128 + 589824 + 393216 + 12582912);

    float* out0 = (float*)d_out;                  // [32, 2048, 384]
    float* dpo  = out0 + (size_t)32 * 2048 * 384; // [32, 512]
    // h1 scratch lives in the d_out region (gather fully overwrites it later)
    u16* h1 = (u16*)d_out;                        // 16384*256 bf16 = 8 MB

    prep_kernel<<<4992, 256, 0, stream>>>(x, w1, w2, xb, Wt1, Wt2, zbuf);

    conv_mfma_kernel<384, 0><<<256, 512, 0, stream>>>(
        xb, Wt1, b1, g1, bb1, nullptr, nullptr, zbuf, (void*)h1);
    conv_mfma_kernel<256, 1><<<256, 512, 0, stream>>>(
        h1, Wt2, b2, g2, bb2, lw, lb, zbuf, (void*)dpo);

    lr_idx_kernel<<<NB, 256, 0, stream>>>(target, idxv);
    lr_gather_kernel<<<24576, 256, 0, stream>>>(x, idxv, out0);
}

// Round 5
// 77.839 us; speedup vs baseline: 4.5545x; 1.1101x over previous
//
#include <hip/hip_runtime.h>
#include <hip/hip_bf16.h>

#define NB   32
#define TMEL 2048

typedef unsigned short u16;
typedef short s8v __attribute__((ext_vector_type(8)));
typedef float f4v __attribute__((ext_vector_type(4)));
typedef u16 u16x8 __attribute__((ext_vector_type(8)));

static __device__ __forceinline__ u16 f2bf(float v) {
    __hip_bfloat16 h = __float2bfloat16(v);
    return *(u16*)&h;
}

// ---------------------------------------------------------------------------
// Fused prep: x->bf16 (blocks [0,3072)), w1 transpose ([3072,4224)),
// w2 transpose ([4224,4992)), lr cumsum+searchsorted ([4992,5024)),
// zbuf zeroing (block 0, tid<8).
// Wt[f][kc*DIN + d] = bf16(w[f][d][kc]);  w is [256][DIN][3]
// ---------------------------------------------------------------------------
__global__ __launch_bounds__(256) void prep_kernel(
    const float* __restrict__ x,
    const float* __restrict__ w1,
    const float* __restrict__ w2,
    const int*   __restrict__ target,
    u16* __restrict__ xb,
    u16* __restrict__ Wt1,
    u16* __restrict__ Wt2,
    int* __restrict__ idxv,
    u16* __restrict__ zbuf)
{
    __shared__ int c[512];
    const int b = blockIdx.x, tid = threadIdx.x;
    if (b == 0 && tid < 8) {
        u16x8 z = {0, 0, 0, 0, 0, 0, 0, 0};
        *(u16x8*)(zbuf + tid * 8) = z;
    }
    if (b < 3072) {
        int i = b * 256 + tid;                    // over 6291456/8
        const f4v* p = (const f4v*)(x + (size_t)i * 8);
        f4v v0 = p[0], v1 = p[1];
        float vv[8] = {v0[0], v0[1], v0[2], v0[3], v1[0], v1[1], v1[2], v1[3]};
        u16x8 r;
        #pragma unroll
        for (int j = 0; j < 8; j++) r[j] = f2bf(vv[j]);
        *(u16x8*)(xb + (size_t)i * 8) = r;
    } else if (b < 3072 + 1152) {
        const int K = 1152, DIN = 384;
        int e = (b - 3072) * 256 + tid;           // over 256*1152
        int f = e / K;
        int rem = e - f * K;
        int kc = rem / DIN;
        int d = rem - kc * DIN;
        Wt1[e] = f2bf(w1[f * K + d * 3 + kc]);
    } else if (b < 4992) {
        const int K = 768, DIN = 256;
        int e = (b - 4224) * 256 + tid;           // over 256*768
        int f = e / K;
        int rem = e - f * K;
        int kc = rem / DIN;
        int d = rem - kc * DIN;
        Wt2[e] = f2bf(w2[f * K + d * 3 + kc]);
    } else {
        // LR index build for batch n
        const int n = b - 4992;
        c[tid]       = target[n * 512 + tid];
        c[tid + 256] = target[n * 512 + 256 + tid];
        __syncthreads();
        for (int off = 1; off < 512; off <<= 1) {
            int v0 = (tid       >= off) ? c[tid       - off] : 0;
            int v1 = (tid + 256 >= off) ? c[tid + 256 - off] : 0;
            __syncthreads();
            c[tid]       += v0;
            c[tid + 256] += v1;
            __syncthreads();
        }
        const int total = c[511];
        for (int t = tid; t < TMEL; t += 256) {
            int lo = 0, hi = 512;
            while (lo < hi) {
                int mid = (lo + hi) >> 1;
                if (c[mid] <= t) lo = mid + 1; else hi = mid;
            }
            idxv[n * TMEL + t] = (t < total) ? min(lo, 511) : -1;
        }
    }
}

// ---------------------------------------------------------------------------
// Fused conv1d(K=3,pad=1) as MFMA GEMM + bias + LayerNorm + ReLU (+ lin dot)
// out[m][f] = sum_k A[m][k] * B[k][f],  A[m][k] = Ain[n, l+kc-1, d] (0 padded)
// k = kc*DIN + d.  Tile 32(M) x 256(F) x BK=64.  256 thr = 4 waves.
// Wave w: rows 0..31, cols 64w..64w+63 -> 2x4 frags of 16x16x32.
// LDS double-buffered; rows slot^=(row&7) swizzled via pre-swizzled global src
// (rule 21) + swizzled ds_read.  Pipelined: stage(t+1) issued BEFORE
// compute(t); ONE __syncthreads per K-step (compiler emits the vmcnt drain).
// Grid 512 = 2 blocks/CU for cross-block latency hiding (m114).
// MODE 0: write bf16 h to out [M][256].  MODE 1: dpo[m] = dot(h, lin_w)+lin_b.
// ---------------------------------------------------------------------------
template<int DIN, int MODE>
__global__ __launch_bounds__(256, 2) void conv_mfma_kernel(
    const u16* __restrict__ Ain,   // [N*512][DIN] bf16
    const u16* __restrict__ Wt,    // [256][3*DIN] bf16
    const float* __restrict__ cb,
    const float* __restrict__ g,
    const float* __restrict__ bb,
    const float* __restrict__ lw,
    const float* __restrict__ lbp,
    const u16* __restrict__ zbuf,  // >=16B zeros
    void* __restrict__ outp)
{
    const int K = 3 * DIN, NT = K / 64;
    __shared__ __align__(128) char AsB[2][32 * 128];    // 2 x 4 KB
    __shared__ __align__(128) char BsB[2][256 * 128];   // 2 x 32 KB
    __shared__ float redS[32 * 4];
    __shared__ float redQ[32 * 4];
    __shared__ float redP[32 * 4];

    const int tid  = threadIdx.x;
    const int lane = tid & 63, wc = tid >> 6;          // 4 waves, wc = col group
    const int lr = lane & 15, q4 = lane >> 4;
    const int m0 = blockIdx.x * 32;
    const int n  = m0 >> 9, l0 = m0 & 511;

    f4v acc[2][4];
    #pragma unroll
    for (int mi = 0; mi < 2; mi++)
        #pragma unroll
        for (int ni = 0; ni < 4; ni++) acc[mi][ni] = {0.f, 0.f, 0.f, 0.f};

    // staging maps (dest linear tid*16; source slot pre-swizzled, rule 21)
    const int a_r    = tid >> 3;                       // A row 0..31
    const int a_slot = (tid & 7) ^ (a_r & 7);
    const int b_r    = tid >> 3;                       // B row base 0..31
    const int b_slot = (tid & 7) ^ (b_r & 7);          // (q*32)&7==0 -> invariant

    // fragment read offsets (swizzled)
    const int aoff0 = (lr) * 128;
    const int aoff1 = (16 + lr) * 128;
    int boff[4];
    #pragma unroll
    for (int ni = 0; ni < 4; ni++) boff[ni] = (64 * wc + 16 * ni + lr) * 128;
    const int slot0 = ((q4)     ^ (lr & 7)) << 4;
    const int slot1 = ((q4 | 4) ^ (lr & 7)) << 4;

    auto stage = [&](int buf, int t) {
        const int k0 = t * 64;
        const int kc = k0 / DIN;
        const int d0 = k0 - kc * DIN;
        const int lp = l0 + a_r + kc - 1;
        const u16* asrc = (lp >= 0 && lp < 512)
            ? (Ain + ((size_t)((n << 9) + lp)) * DIN + d0 + a_slot * 8)
            : zbuf;
        __builtin_amdgcn_global_load_lds(
            (const __attribute__((address_space(1))) void*)asrc,
            (__attribute__((address_space(3))) void*)(AsB[buf] + tid * 16), 16, 0, 0);
        const u16* bsrc = Wt + (size_t)b_r * K + k0 + b_slot * 8;
        #pragma unroll
        for (int q = 0; q < 8; q++) {
            __builtin_amdgcn_global_load_lds(
                (const __attribute__((address_space(1))) void*)(bsrc + (size_t)q * 32 * K),
                (__attribute__((address_space(3))) void*)(BsB[buf] + q * 4096 + tid * 16),
                16, 0, 0);
        }
    };

    auto compute = [&](int buf) {
        #pragma unroll
        for (int kk = 0; kk < 2; kk++) {
            const int sl = kk ? slot1 : slot0;
            s8v a0 = *(const s8v*)(AsB[buf] + aoff0 + sl);
            s8v a1 = *(const s8v*)(AsB[buf] + aoff1 + sl);
            s8v b0 = *(const s8v*)(BsB[buf] + boff[0] + sl);
            s8v b1 = *(const s8v*)(BsB[buf] + boff[1] + sl);
            s8v b2 = *(const s8v*)(BsB[buf] + boff[2] + sl);
            s8v b3 = *(const s8v*)(BsB[buf] + boff[3] + sl);
            acc[0][0] = __builtin_amdgcn_mfma_f32_16x16x32_bf16(a0, b0, acc[0][0], 0, 0, 0);
            acc[0][1] = __builtin_amdgcn_mfma_f32_16x16x32_bf16(a0, b1, acc[0][1], 0, 0, 0);
            acc[0][2] = __builtin_amdgcn_mfma_f32_16x16x32_bf16(a0, b2, acc[0][2], 0, 0, 0);
            acc[0][3] = __builtin_amdgcn_mfma_f32_16x16x32_bf16(a0, b3, acc[0][3], 0, 0, 0);
            acc[1][0] = __builtin_amdgcn_mfma_f32_16x16x32_bf16(a1, b0, acc[1][0], 0, 0, 0);
            acc[1][1] = __builtin_amdgcn_mfma_f32_16x16x32_bf16(a1, b1, acc[1][1], 0, 0, 0);
            acc[1][2] = __builtin_amdgcn_mfma_f32_16x16x32_bf16(a1, b2, acc[1][2], 0, 0, 0);
            acc[1][3] = __builtin_amdgcn_mfma_f32_16x16x32_bf16(a1, b3, acc[1][3], 0, 0, 0);
        }
    };

    // pipelined main loop: one barrier per K-step, stage(t+1) overlaps compute(t)
    stage(0, 0);
    __syncthreads();
    int cur = 0;
    for (int t = 0; t < NT; ++t) {
        if (t + 1 < NT) stage(cur ^ 1, t + 1);
        compute(cur);
        __syncthreads();
        cur ^= 1;
    }

    // ---- epilogue: bias + LN + ReLU (+ dot) ----
    // acc[mi][ni][reg] = C[m0 + 16mi + 4*q4 + reg][64wc + 16ni + lr]
    float cbv[4], gv[4], bbv[4], lwv[4];
    int col[4];
    #pragma unroll
    for (int ni = 0; ni < 4; ni++) {
        col[ni] = 64 * wc + 16 * ni + lr;
        cbv[ni] = cb[col[ni]]; gv[ni] = g[col[ni]]; bbv[ni] = bb[col[ni]];
        if (MODE == 1) lwv[ni] = lw[col[ni]];
    }

    float sv[2][4], sq[2][4];
    #pragma unroll
    for (int mi = 0; mi < 2; mi++)
        #pragma unroll
        for (int reg = 0; reg < 4; reg++) {
            float s = 0.f, q = 0.f;
            #pragma unroll
            for (int ni = 0; ni < 4; ni++) {
                float v = acc[mi][ni][reg] + cbv[ni];
                s += v; q += v * v;
            }
            #pragma unroll
            for (int msk = 1; msk < 16; msk <<= 1) {
                s += __shfl_xor(s, msk);
                q += __shfl_xor(q, msk);
            }
            sv[mi][reg] = s; sq[mi][reg] = q;
        }
    if (lr == 0) {
        #pragma unroll
        for (int mi = 0; mi < 2; mi++)
            #pragma unroll
            for (int reg = 0; reg < 4; reg++) {
                int rl = 16 * mi + 4 * q4 + reg;
                redS[rl * 4 + wc] = sv[mi][reg];
                redQ[rl * 4 + wc] = sq[mi][reg];
            }
    }
    __syncthreads();

    float mean_[2][4], rs_[2][4];
    #pragma unroll
    for (int mi = 0; mi < 2; mi++)
        #pragma unroll
        for (int reg = 0; reg < 4; reg++) {
            int rl = 16 * mi + 4 * q4 + reg;
            float4 ps = *(float4*)&redS[rl * 4];
            float4 pq = *(float4*)&redQ[rl * 4];
            float mean = (ps.x + ps.y + ps.z + ps.w) * (1.f / 256.f);
            float var  = (pq.x + pq.y + pq.z + pq.w) * (1.f / 256.f) - mean * mean;
            mean_[mi][reg] = mean;
            rs_[mi][reg]   = rsqrtf(var + 1e-5f);
        }

    if (MODE == 0) {
        u16* hout = (u16*)outp;
        #pragma unroll
        for (int mi = 0; mi < 2; mi++)
            #pragma unroll
            for (int reg = 0; reg < 4; reg++) {
                int rl = 16 * mi + 4 * q4 + reg;
                #pragma unroll
                for (int ni = 0; ni < 4; ni++) {
                    float v = acc[mi][ni][reg] + cbv[ni];
                    float o = fmaxf(0.f, (v - mean_[mi][reg]) * rs_[mi][reg] * gv[ni] + bbv[ni]);
                    hout[(size_t)(m0 + rl) * 256 + col[ni]] = f2bf(o);
                }
            }
    } else {
        float pp[2][4];
        #pragma unroll
        for (int mi = 0; mi < 2; mi++)
            #pragma unroll
            for (int reg = 0; reg < 4; reg++) {
                float p = 0.f;
                #pragma unroll
                for (int ni = 0; ni < 4; ni++) {
                    float v = acc[mi][ni][reg] + cbv[ni];
                    float o = fmaxf(0.f, (v - mean_[mi][reg]) * rs_[mi][reg] * gv[ni] + bbv[ni]);
                    p += o * lwv[ni];
                }
                #pragma unroll
                for (int msk = 1; msk < 16; msk <<= 1) p += __shfl_xor(p, msk);
                pp[mi][reg] = p;
            }
        if (lr == 0) {
            #pragma unroll
            for (int mi = 0; mi < 2; mi++)
                #pragma unroll
                for (int reg = 0; reg < 4; reg++) {
                    int rl = 16 * mi + 4 * q4 + reg;
                    redP[rl * 4 + wc] = pp[mi][reg];
                }
        }
        __syncthreads();
        if (tid < 32) {
            float* dpo = (float*)outp;
            float4 p4 = *(float4*)&redP[tid * 4];
            dpo[m0 + tid] = p4.x + p4.y + p4.z + p4.w + lbp[0];
        }
    }
}

// ---------------------------------------------------------------------------
// LR gather: rows of x -> out [N, T, 384]; 2 x f4 per thread (same row,
// slots j and j+48); nontemporal stores (write-once stream).
// ---------------------------------------------------------------------------
__global__ void lr_gather_kernel(const float* __restrict__ x,
                                 const int* __restrict__ idxv,
                                 float* __restrict__ out) {
    int gid = blockIdx.x * 256 + threadIdx.x;   // over N*T*48
    int f4  = gid % 48;
    int row = gid / 48;
    int n   = row >> 11;
    int ie  = idxv[row];
    f4v v0 = {0.f, 0.f, 0.f, 0.f}, v1 = v0;
    if (ie >= 0) {
        const float* src = &x[((size_t)(n << 9) + ie) * 384];
        v0 = *(const f4v*)&src[f4 * 4];
        v1 = *(const f4v*)&src[(f4 + 48) * 4];
    }
    float* dst = &out[(size_t)row * 384];
    __builtin_nontemporal_store(v0, (f4v*)&dst[f4 * 4]);
    __builtin_nontemporal_store(v1, (f4v*)&dst[(f4 + 48) * 4]);
}

// ---------------------------------------------------------------------------
extern "C" void kernel_launch(void* const* d_in, const int* in_sizes, int n_in,
                              void* d_out, int out_size, void* d_ws, size_t ws_size,
                              hipStream_t stream) {
    const float* x   = (const float*)d_in[0];
    const float* w1  = (const float*)d_in[1];
    const float* b1  = (const float*)d_in[2];
    const float* g1  = (const float*)d_in[3];
    const float* bb1 = (const float*)d_in[4];
    const float* w2  = (const float*)d_in[5];
    const float* b2  = (const float*)d_in[6];
    const float* g2  = (const float*)d_in[7];
    const float* bb2 = (const float*)d_in[8];
    const float* lw  = (const float*)d_in[9];
    const float* lb  = (const float*)d_in[10];
    const int* target = (const int*)d_in[11];

    // ws layout (bytes): zbuf 128 | Wt1 589824 | Wt2 393216 | xb 12582912 | idxv 262144
    char* wsb  = (char*)d_ws;
    u16*  zbuf = (u16*)wsb;
    u16*  Wt1  = (u16*)(wsb + 128);
    u16*  Wt2  = (u16*)(wsb + 128 + 589824);
    u16*  xb   = (u16*)(wsb + 128 + 589824 + 393216);
    int*  idxv = (int*)(wsb + 128 + 589824 + 393216 + 12582912);

    float* out0 = (float*)d_out;                  // [32, 2048, 384]
    float* dpo  = out0 + (size_t)32 * 2048 * 384; // [32, 512]
    // h1 scratch lives in the d_out region (gather fully overwrites it later)
    u16* h1 = (u16*)d_out;                        // 16384*256 bf16 = 8 MB

    prep_kernel<<<5024, 256, 0, stream>>>(x, w1, w2, target, xb, Wt1, Wt2, idxv, zbuf);

    conv_mfma_kernel<384, 0><<<512, 256, 0, stream>>>(
        xb, Wt1, b1, g1, bb1, nullptr, nullptr, zbuf, (void*)h1);
    conv_mfma_kernel<256, 1><<<512, 256, 0, stream>>>(
        h1, Wt2, b2, g2, bb2, lw, lb, zbuf, (void*)dpo);

    lr_gather_kernel<<<12288, 256, 0, stream>>>(x, idxv, out0);
}